// Round 1
// 838.548 us; speedup vs baseline: 1.2995x; 1.2995x over previous
//
#include <hip/hip_runtime.h>

#define D_INPUT 768
#define D_HID   16384
#define BATCH   8192
#define TOPK    32

using f32x4     = __attribute__((ext_vector_type(4))) float;
using bf16x8    = __attribute__((ext_vector_type(8))) __bf16;
using ushort8_t = __attribute__((ext_vector_type(8))) unsigned short;

__device__ __forceinline__ unsigned short f2bf(float f) {
  union { float f; unsigned u; } v{f};
  return (unsigned short)((v.u + 0x7FFFu + ((v.u >> 16) & 1u)) >> 16);  // RNE
}
__device__ __forceinline__ float bf2f(unsigned short u) {
  union { unsigned u; float f; } v{(unsigned)u << 16};
  return v.f;
}

// async global->LDS, 16B per lane; LDS dest = wave-uniform base + lane*16.
__device__ __forceinline__ void async_copy16(const void* g, void* l) {
  __builtin_amdgcn_global_load_lds(
      (__attribute__((address_space(1))) void*)(unsigned long long)g,
      (__attribute__((address_space(3))) void*)(unsigned)(unsigned long long)l,
      16, 0, 0);
}

// Replica of OpenBLAS sgemm on Zen4/Zen5 hosts (SkylakeX/Cooperlake kernels):
// SGEMM_DEFAULT_Q = 320 -> K panels [320, 224, 224]; each panel a single
// ascending fma chain; C updated panel-by-panel -> ((p0 + p1) + p2).
// The three chains are INDEPENDENT, so we interleave them for 3-way ILP
// (each chain's internal order is untouched -> bit-identical result, ~2.4x
// lower dependent-FMA latency than three sequential loops).
__device__ float blas_dot(const float* __restrict__ xr,
                          const float* __restrict__ wp) {
  float p0 = 0.f, p1 = 0.f, p2 = 0.f;
  #pragma unroll 4
  for (int i = 0; i < 224; ++i) {
    p0 = __builtin_fmaf(xr[i],       wp[i],       p0);
    p1 = __builtin_fmaf(xr[320 + i], wp[320 + i], p1);
    p2 = __builtin_fmaf(xr[544 + i], wp[544 + i], p2);
  }
  #pragma unroll 4
  for (int i = 224; i < 320; ++i) p0 = __builtin_fmaf(xr[i], wp[i], p0);
  return (p0 + p1) + p2;
}

// ---------------- fp32 -> bf16 convert (vectorized) ----------------
__global__ void cvt_f32_bf16(const float* __restrict__ in,
                             unsigned short* __restrict__ out, int n) {
  int i = (blockIdx.x * 256 + threadIdx.x) * 4;
  if (i < n) {
    float4 f = *(const float4*)(in + i);
    ushort4 o;
    o.x = f2bf(f.x); o.y = f2bf(f.y); o.z = f2bf(f.z); o.w = f2bf(f.w);
    *(ushort4*)(out + i) = o;
  }
}

// ---------------- W_dec [768][16384] -> WT bf16 [16384][768] ----------------
__global__ void transpose_wdec(const float* __restrict__ W,
                               unsigned short* __restrict__ WT) {
  __shared__ float tile[32][33];
  const int h0 = blockIdx.x * 32;   // hidden
  const int i0 = blockIdx.y * 32;   // d_in
  const int tx = threadIdx.x, ty = threadIdx.y;  // 32 x 8
  #pragma unroll
  for (int j = 0; j < 32; j += 8)
    tile[ty + j][tx] = W[(size_t)(i0 + ty + j) * D_HID + h0 + tx];
  __syncthreads();
  #pragma unroll
  for (int j = 0; j < 32; j += 8)
    WT[(size_t)(h0 + ty + j) * D_INPUT + i0 + tx] = f2bf(tile[tx][ty + j]);
}

// ---------------- encode: Z = relu(Xc * Wb^T + b_enc), bf16 MFMA ----------------
__global__ __launch_bounds__(256) void encode_kernel(
    const unsigned short* __restrict__ Xc,   // [rows][768] bf16 (chunk base)
    const unsigned short* __restrict__ Wb,   // [16384][768] bf16
    const float* __restrict__ b_enc,
    unsigned short* __restrict__ Z)          // [rows][16384] bf16, relu'd
{
  __shared__ unsigned short As[128 * 32];  // 8 KB, row-major [row][k]
  __shared__ unsigned short Bs[128 * 32];

  const int tid  = threadIdx.x;
  const int wave = tid >> 6;
  const int lane = tid & 63;
  const int tileN = blockIdx.x;
  const int tileM = blockIdx.y;

  const int e0 = wave * 512 + lane * 8;
  const int r0 = e0 >> 5;          // tile row 0..63 (second copy adds 64)
  const int k0 = e0 & 31;

  const unsigned short* gA = Xc + (size_t)(tileM * 128 + r0) * D_INPUT + k0;
  const unsigned short* gB = Wb + (size_t)(tileN * 128 + r0) * D_INPUT + k0;
  unsigned short* lA0 = As + wave * 512;         // wave-uniform LDS bases
  unsigned short* lA1 = As + wave * 512 + 2048;
  unsigned short* lB0 = Bs + wave * 512;
  unsigned short* lB1 = Bs + wave * 512 + 2048;

  const int wr = wave >> 1, wc = wave & 1;
  const int lrow = lane & 15;
  const int lk   = (lane >> 4) * 8;

  f32x4 acc[4][4] = {};

  for (int kt = 0; kt < D_INPUT / 32; ++kt) {
    __syncthreads();
    async_copy16(gA, lA0);
    async_copy16(gA + 64 * D_INPUT, lA1);
    async_copy16(gB, lB0);
    async_copy16(gB + 64 * D_INPUT, lB1);
    gA += 32; gB += 32;
    __builtin_amdgcn_s_waitcnt(0);
    __syncthreads();

    bf16x8 af[4], bfr[4];
    #pragma unroll
    for (int mf = 0; mf < 4; ++mf)
      af[mf] = __builtin_bit_cast(bf16x8,
        *(const ushort8_t*)(As + (wr * 64 + mf * 16 + lrow) * 32 + lk));
    #pragma unroll
    for (int nf = 0; nf < 4; ++nf)
      bfr[nf] = __builtin_bit_cast(bf16x8,
        *(const ushort8_t*)(Bs + (wc * 64 + nf * 16 + lrow) * 32 + lk));
    #pragma unroll
    for (int mf = 0; mf < 4; ++mf)
      #pragma unroll
      for (int nf = 0; nf < 4; ++nf)
        acc[mf][nf] = __builtin_amdgcn_mfma_f32_16x16x32_bf16(
            af[mf], bfr[nf], acc[mf][nf], 0, 0, 0);
  }

  // epilogue: C/D layout col=lane&15, row=(lane>>4)*4+reg (m89/m91-verified)
  const int rowBase = tileM * 128 + wr * 64;
  const int colBase = tileN * 128 + wc * 64;
  #pragma unroll
  for (int nf = 0; nf < 4; ++nf) {
    const int col = colBase + nf * 16 + lrow;
    const float bias = b_enc[col];
    #pragma unroll
    for (int mf = 0; mf < 4; ++mf) {
      const int row = rowBase + mf * 16 + (lane >> 4) * 4;
      #pragma unroll
      for (int i = 0; i < 4; ++i) {
        float v = acc[mf][nf][i] + bias;
        v = v > 0.f ? v : 0.f;
        Z[(size_t)(row + i) * D_HID + col] = f2bf(v);
      }
    }
  }
}

// Wave-0 suffix scan over a 256-bin histogram: find the highest bin b such
// that base + count(bins > b) + count(bin b) >= TOPK. Writes {bin, count
// strictly above bin} from the single winning lane. Replaces the serial
// tid==0 256-iteration loop.
__device__ __forceinline__ void scan_suffix(const unsigned int* __restrict__ h,
                                            int base, int* outBin, int* outCum,
                                            int l) {
  unsigned int h0 = h[255 - 4 * l];
  unsigned int h1 = h[254 - 4 * l];
  unsigned int h2 = h[253 - 4 * l];
  unsigned int h3 = h[252 - 4 * l];
  unsigned int c0 = h0, c1 = c0 + h1, c2 = c1 + h2, c3 = c2 + h3;
  unsigned int inc = c3;                       // inclusive scan of lane totals
  #pragma unroll
  for (int d = 1; d < 64; d <<= 1) {
    unsigned int o = __shfl_up(inc, d, 64);
    if (l >= d) inc += o;
  }
  unsigned int excl = (unsigned int)base + inc - c3;  // count above lane's bins
  int bFound = -1; int cumB = 0;
  if      (excl + c0 >= TOPK) { bFound = 255 - 4 * l; cumB = (int)excl; }
  else if (excl + c1 >= TOPK) { bFound = 254 - 4 * l; cumB = (int)(excl + c0); }
  else if (excl + c2 >= TOPK) { bFound = 253 - 4 * l; cumB = (int)(excl + c1); }
  else if (excl + c3 >= TOPK) { bFound = 252 - 4 * l; cumB = (int)(excl + c2); }
  unsigned long long m = __ballot(bFound >= 0);
  if (m) {
    int w = (int)__builtin_ctzll(m);           // lowest lane = highest bins
    if (l == w) { *outBin = bFound; *outCum = cumB; }
  } else if (l == 0) { *outBin = -1; *outCum = base; }
}

// ---------------- top-32 per row; boundary + values via OpenBLAS replica -------
// v2: Z row held in registers (8 x ushort8, coalesced identically to the old
// LDS copy); 8-copy privatized histogram (bin*8 + lane&7) kills the 64-way
// same-address LDS-atomic serialization on the ~4 hot exponent bins;
// suffix scans parallelized on wave 0. Selection semantics (exact bf16
// rank-32 threshold + MARGIN band + fp32 OpenBLAS-replica recompute) are
// unchanged, so the selected set and values are identical to v1.
__global__ __launch_bounds__(256, 5) void topk_kernel(
    const unsigned short* __restrict__ Z,    // chunk base [rows][16384]
    const float* __restrict__ X,             // full fp32 [8192][768]
    const float* __restrict__ W_enc,         // fp32 [16384][768]
    const float* __restrict__ b_enc,
    int* __restrict__ sel_idx,               // [8192][32]
    float* __restrict__ sel_val,
    int rowOff)
{
  __shared__ float xrow[D_INPUT];            // 3 KB
  __shared__ unsigned int hist[256 * 8];     // 8 KB, 8 copies per bin
  __shared__ unsigned int htot[256];         // 1 KB, totals / pass-2 hist
  __shared__ int sB, sCum, sLo;
  __shared__ int def_cnt, amb_cnt, out_cnt;
  __shared__ int   def_idx[40];
  __shared__ float def_val[40];
  __shared__ int   amb_idx[64];
  __shared__ float amb_val[64];

  const int lrowB = blockIdx.x;            // row within chunk
  const int row   = rowOff + lrowB;        // absolute row
  const int tid   = threadIdx.x;
  const int lane  = tid & 63;

  // ---- Z row -> registers (element i = tid*8 + j*2048 + e; 1KB/wave/j) ----
  ushort8_t zv[8];
  {
    const ushort8_t* src = (const ushort8_t*)(Z + (size_t)lrowB * D_HID);
    #pragma unroll
    for (int j = 0; j < 8; ++j) zv[j] = src[tid + j * 256];
  }
  if (tid < D_INPUT / 4)
    ((float4*)xrow)[tid] = ((const float4*)(X + (size_t)row * D_INPUT))[tid];
  #pragma unroll
  for (int c = 0; c < 8; ++c) hist[tid + c * 256] = 0;
  if (tid == 0) { def_cnt = 0; amb_cnt = 0; out_cnt = 0; sLo = 0; }
  __syncthreads();

  // ---- pass 1: high byte (zeros can't be in a positive top-32) ----
  #pragma unroll
  for (int j = 0; j < 8; ++j) {
    #pragma unroll
    for (int e = 0; e < 8; ++e) {
      unsigned short k = (unsigned short)zv[j][e];
      if (k) atomicAdd(&hist[(((unsigned)k >> 8) << 3) + (lane & 7)], 1u);
    }
  }
  __syncthreads();
  {
    unsigned int s = 0;
    #pragma unroll
    for (int c = 0; c < 8; ++c) s += hist[tid * 8 + c];
    htot[tid] = s;
  }
  __syncthreads();
  if (tid < 64) scan_suffix(htot, 0, &sB, &sCum, tid);
  __syncthreads();

  const int bHi  = sB;
  const int cum1 = sCum;
  htot[tid] = 0;                           // reuse as pass-2 histogram
  __syncthreads();

  // ---- pass 2: low byte within bin bHi (sparse -> single copy is fine) ----
  if (bHi >= 0) {
    #pragma unroll
    for (int j = 0; j < 8; ++j) {
      #pragma unroll
      for (int e = 0; e < 8; ++e) {
        unsigned short k = (unsigned short)zv[j][e];
        if (k && ((unsigned)k >> 8) == (unsigned)bHi)
          atomicAdd(&htot[k & 255], 1u);
      }
    }
  }
  __syncthreads();
  if (bHi >= 0 && tid < 64) {
    int dummy;
    scan_suffix(htot, cum1, &sLo, &dummy, tid);
  }
  __syncthreads();

  const int T = (bHi >= 0) ? ((bHi << 8) | sLo) : 0;
  const bool deg = (T == 0);              // fewer than 32 positive activations
  const float v32 = bf2f((unsigned short)T);
  const float MARGIN = 0.025f;            // > 2*(bf16 quant 0.0078 + MFMA noise ~2e-3)
  const float vhi = v32 + MARGIN, vlo = v32 - MARGIN;

  // ---- candidate collection from registers ----
  #pragma unroll
  for (int j = 0; j < 8; ++j) {
    #pragma unroll
    for (int e = 0; e < 8; ++e) {
      unsigned short k = (unsigned short)zv[j][e];
      if (!k) continue;
      const float v = bf2f(k);
      const int i = tid * 8 + j * 2048 + e;
      if (deg || v > vhi) {                  // provably in ref's top-32
        int p = atomicAdd(&def_cnt, 1);
        if (p < 40) def_idx[p] = i;
      } else if (v >= vlo) {                 // boundary-ambiguous
        int p = atomicAdd(&amb_cnt, 1);
        if (p < 64) amb_idx[p] = i;
      }
    }
  }
  __syncthreads();

  const int nAmb = deg ? 0 : (amb_cnt < 64 ? amb_cnt : 64);
  const int nDef = def_cnt < 40 ? def_cnt : 40;

  // OpenBLAS-replica fp32 recompute: one THREAD per candidate (def + amb).
  for (int c = tid; c < nDef + nAmb; c += 256) {
    const int h = (c < nDef) ? def_idx[c] : amb_idx[c - nDef];
    float acc = blas_dot(xrow, W_enc + (size_t)h * D_INPUT) + b_enc[h];
    float v = acc > 0.f ? acc : 0.f;
    if (c < nDef) def_val[c] = v; else amb_val[c - nDef] = v;
  }
  __syncthreads();

  const int need = TOPK - nDef;
  if (tid < nDef) {
    sel_idx[row * TOPK + tid] = def_idx[tid];
    sel_val[row * TOPK + tid] = def_val[tid];
  }
  if (tid < nAmb) {
    const float v = amb_val[tid];
    const int h = amb_idx[tid];
    int rank = 0;
    for (int j = 0; j < nAmb; ++j) {
      const float vj = amb_val[j];
      if (vj > v || (vj == v && amb_idx[j] < h)) ++rank;   // stable, idx-asc ties
    }
    if (rank < need) {
      int p = atomicAdd(&out_cnt, 1);
      sel_idx[row * TOPK + nDef + p] = h;
      sel_val[row * TOPK + nDef + p] = v;
    }
  }
  __syncthreads();
  const int nSel = nDef + (need < nAmb ? need : nAmb);
  if (tid >= nSel && tid < TOPK) {         // pad (only when <32 positives)
    sel_idx[row * TOPK + tid] = 0;
    sel_val[row * TOPK + tid] = 0.f;
  }
}

// ---------------- decode: out = b_dec + sum_32 val * WT[idx,:] (bf16 WT) ------
__global__ __launch_bounds__(256) void decode_kernel(
    const unsigned short* __restrict__ WT,   // [16384][768] bf16
    const int* __restrict__ sel_idx,
    const float* __restrict__ sel_val,
    const float* __restrict__ b_dec,
    float* __restrict__ out)                 // [8192][768]
{
  __shared__ int sidx[TOPK];
  __shared__ float sval[TOPK];
  const int row = blockIdx.x, tid = threadIdx.x;
  if (tid < TOPK) {
    sidx[tid] = sel_idx[row * TOPK + tid];
    sval[tid] = sel_val[row * TOPK + tid];
  }
  __syncthreads();
  float a0 = b_dec[tid], a1 = b_dec[tid + 256], a2 = b_dec[tid + 512];
  #pragma unroll 8
  for (int s = 0; s < TOPK; ++s) {
    const unsigned short* w = WT + (size_t)sidx[s] * D_INPUT;
    const float v = sval[s];
    a0 += v * bf2f(w[tid]);
    a1 += v * bf2f(w[tid + 256]);
    a2 += v * bf2f(w[tid + 512]);
  }
  float* o = out + (size_t)row * D_INPUT;
  o[tid] = a0; o[tid + 256] = a1; o[tid + 512] = a2;
}

// ---------------- diagnostic fallback: out = broadcast b_dec ----------------
__global__ void diag_fill(const float* __restrict__ b_dec, float* __restrict__ out) {
  const int row = blockIdx.x, tid = threadIdx.x;
  float* o = out + (size_t)row * D_INPUT;
  o[tid] = b_dec[tid]; o[tid + 256] = b_dec[tid + 256]; o[tid + 512] = b_dec[tid + 512];
}

extern "C" void kernel_launch(void* const* d_in, const int* in_sizes, int n_in,
                              void* d_out, int out_size, void* d_ws, size_t ws_size,
                              hipStream_t stream) {
  (void)in_sizes; (void)n_in; (void)out_size;
  const float* x     = (const float*)d_in[0];
  const float* W_enc = (const float*)d_in[1];
  const float* b_enc = (const float*)d_in[2];
  const float* W_dec = (const float*)d_in[3];
  const float* b_dec = (const float*)d_in[4];
  float* out = (float*)d_out;

  // ws layout: fixed buffers (~62 MB) first, Z chunk buffer in the remainder
  auto aln = [](size_t v) { return (v + 255) & ~(size_t)255; };
  char* ws = (char*)d_ws;
  size_t oWT = 0;
  size_t oWb = aln(oWT + (size_t)D_HID * D_INPUT * 2);   // WT bf16: 24 MB
  size_t oXb = aln(oWb + (size_t)D_HID * D_INPUT * 2);   // Wb bf16: 24 MB
  size_t oSI = aln(oXb + (size_t)BATCH * D_INPUT * 2);   // Xb bf16: 12 MB
  size_t oSV = aln(oSI + (size_t)BATCH * TOPK * 4);      // sel_idx: 1 MB
  size_t oZ  = aln(oSV + (size_t)BATCH * TOPK * 4);      // sel_val: 1 MB

  unsigned short* WTb = (unsigned short*)(ws + oWT);
  unsigned short* Wb  = (unsigned short*)(ws + oWb);
  unsigned short* Xb  = (unsigned short*)(ws + oXb);
  int*   sel_idx = (int*)(ws + oSI);
  float* sel_val = (float*)(ws + oSV);
  unsigned short* Zb = (unsigned short*)(ws + oZ);

  size_t zcap = ws_size > oZ ? ws_size - oZ : 0;
  long long chunkL = (long long)(zcap / ((size_t)D_HID * 2));
  int chunk = (int)(chunkL & ~127LL);                    // multiple of 128 rows
  if (chunk > BATCH) chunk = BATCH;
  if (chunk <= 0) {                                      // ws too small: signal
    diag_fill<<<dim3(BATCH), 256, 0, stream>>>(b_dec, out);
    return;
  }

  cvt_f32_bf16<<<dim3(BATCH * D_INPUT / 4 / 256), 256, 0, stream>>>(
      x, Xb, BATCH * D_INPUT);
  cvt_f32_bf16<<<dim3(D_HID * D_INPUT / 4 / 256), 256, 0, stream>>>(
      W_enc, Wb, D_HID * D_INPUT);
  transpose_wdec<<<dim3(D_HID / 32, D_INPUT / 32), dim3(32, 8), 0, stream>>>(
      W_dec, WTb);

  for (int r0 = 0; r0 < BATCH; r0 += chunk) {
    const int rows = (BATCH - r0) < chunk ? (BATCH - r0) : chunk;  // multiple of 128
    encode_kernel<<<dim3(D_HID / 128, rows / 128), 256, 0, stream>>>(
        Xb + (size_t)r0 * D_INPUT, Wb, b_enc, Zb);
    topk_kernel<<<dim3(rows), 256, 0, stream>>>(
        Zb, x, W_enc, b_enc, sel_idx, sel_val, r0);
  }

  decode_kernel<<<dim3(BATCH), 256, 0, stream>>>(WTb, sel_idx, sel_val, b_dec, out);
}